// Round 10
// baseline (1898.879 us; speedup 1.0000x reference)
//
#include <hip/hip_runtime.h>
#include <stdint.h>

typedef __bf16 bf16;
typedef __bf16 bf16x4 __attribute__((ext_vector_type(4)));
typedef __bf16 bf16x8 __attribute__((ext_vector_type(8)));
typedef float  f32x4  __attribute__((ext_vector_type(4)));

__device__ __forceinline__ int clampi(int v, int n) { return (v < 0 || v >= n) ? 0 : v; }

__device__ __forceinline__ void gload16(const void* g, void* l) {
  __builtin_amdgcn_global_load_lds((const __attribute__((address_space(1))) void*)g,
                                   (__attribute__((address_space(3))) void*)l, 16, 0, 0);
}

// W [rows][256] f32 -> Wt [256][krows] bf16 (transpose of row-slice [krow0, krow0+krows))
__global__ void wtcvtT_kernel(const float* __restrict__ W, bf16* __restrict__ Wt,
                              int krows, int krow0) {
  int idx = blockIdx.x * 256 + threadIdx.x;
  if (idx >= krows * 256) return;
  int k = idx >> 8, n = idx & 255;
  Wt[(size_t)n * krows + k] = (bf16)W[(size_t)(krow0 + k) * 256 + n];
}

// ---------------- CSR build ----------------
__global__ void hist_kernel(const int* __restrict__ dst, int E, int* __restrict__ cnt, int N) {
  int e = blockIdx.x * 256 + threadIdx.x;
  if (e < E) atomicAdd(&cnt[clampi(dst[e], N)], 1);
}

__global__ void scan_block_kernel(const int* __restrict__ cnt, int N,
                                  int* __restrict__ incl, int* __restrict__ bsums) {
  __shared__ int sd[256];
  int t = threadIdx.x, bid = blockIdx.x;
  int base = bid * 1024 + t * 4;
  int v0 = (base + 0 < N) ? cnt[base + 0] : 0;
  int v1 = (base + 1 < N) ? cnt[base + 1] : 0;
  int v2 = (base + 2 < N) ? cnt[base + 2] : 0;
  int v3 = (base + 3 < N) ? cnt[base + 3] : 0;
  int s1 = v0 + v1, s2 = s1 + v2, s3 = s2 + v3;
  sd[t] = s3;
  __syncthreads();
  for (int off = 1; off < 256; off <<= 1) {
    int x = 0;
    if (t >= off) x = sd[t - off];
    __syncthreads();
    sd[t] += x;
    __syncthreads();
  }
  int excl = sd[t] - s3;
  if (base + 0 < N) incl[base + 0] = excl + v0;
  if (base + 1 < N) incl[base + 1] = excl + s1;
  if (base + 2 < N) incl[base + 2] = excl + s2;
  if (base + 3 < N) incl[base + 3] = excl + s3;
  if (t == 255) bsums[bid] = sd[255];
}

__global__ void scan_sums_kernel(const int* __restrict__ bsums, int nb, int* __restrict__ bexcl) {
  __shared__ int sd[256];
  int t = threadIdx.x;
  int v = (t < nb) ? bsums[t] : 0;
  sd[t] = v;
  __syncthreads();
  for (int off = 1; off < 256; off <<= 1) {
    int x = 0;
    if (t >= off) x = sd[t - off];
    __syncthreads();
    sd[t] += x;
    __syncthreads();
  }
  if (t < nb) bexcl[t] = sd[t] - v;
}

__global__ void scan_add_kernel(const int* __restrict__ incl, const int* __restrict__ bexcl,
                                int N, int* __restrict__ offs) {
  int i = blockIdx.x * 256 + threadIdx.x;
  if (i < N) offs[i + 1] = incl[i] + bexcl[i >> 10];
  if (i == 0) offs[0] = 0;
}

__global__ void scatter_kernel(const int* __restrict__ dst, int E, const int* __restrict__ offs,
                               int* __restrict__ cursor, int* __restrict__ elist, int N) {
  int e = blockIdx.x * 256 + threadIdx.x;
  if (e < E) {
    int d = clampi(dst[e], N);
    int p = atomicAdd(&cursor[d], 1);
    elist[offs[d] + p] = e;
  }
}

// ---------------- segment sum (one wave per node, 4 cols/lane) ----------------
template <int WHERE, int XF32>
__global__ void segsum_kernel(const bf16* __restrict__ H, const int* __restrict__ elist,
                              const int* __restrict__ offs, const float* __restrict__ xf,
                              const bf16* __restrict__ xb, bf16* __restrict__ out, int N) {
  int lane = threadIdx.x & 63;
  int node = blockIdx.x * 4 + (threadIdx.x >> 6);
  if (node >= N) return;
  int beg = offs[node], end = offs[node + 1];
  float a0 = 0.f, a1 = 0.f, a2 = 0.f, a3 = 0.f;
  for (int p = beg; p < end; ++p) {
    int e = elist[p];
    bf16x4 v = ((const bf16x4*)(H + (size_t)e * 256))[lane];
    a0 += (float)v[0]; a1 += (float)v[1]; a2 += (float)v[2]; a3 += (float)v[3];
  }
  if (WHERE) {
    float s = a0 + a1 + a2 + a3;
    for (int off = 1; off < 64; off <<= 1) s += __shfl_xor(s, off);
    if (s == 0.f) {  // no (nonzero) incoming messages -> pass through x
      bf16x4 o;
      if (XF32) {
        float4 xv = ((const float4*)(xf))[(size_t)node * 64 + lane];
        o[0] = (bf16)xv.x; o[1] = (bf16)xv.y; o[2] = (bf16)xv.z; o[3] = (bf16)xv.w;
      } else {
        o = ((const bf16x4*)(xb + (size_t)node * 256))[lane];
      }
      ((bf16x4*)(out + (size_t)node * 256))[lane] = o;
      return;
    }
  }
  bf16x4 o = {(bf16)a0, (bf16)a1, (bf16)a2, (bf16)a3};
  ((bf16x4*)(out + (size_t)node * 256))[lane] = o;
}

// ---------------- mean pool over contiguous groups ----------------
template <int OUTF32>
__global__ void pool_kernel(const bf16* __restrict__ h, bf16* __restrict__ outb,
                            float* __restrict__ outf, int Nout, int cnt) {
  int lane = threadIdx.x & 63;
  int node = blockIdx.x * 4 + (threadIdx.x >> 6);
  if (node >= Nout) return;
  float a0 = 0.f, a1 = 0.f, a2 = 0.f, a3 = 0.f;
  size_t base = (size_t)node * cnt;
  for (int p = 0; p < cnt; ++p) {
    bf16x4 v = ((const bf16x4*)(h + (base + p) * 256))[lane];
    a0 += (float)v[0]; a1 += (float)v[1]; a2 += (float)v[2]; a3 += (float)v[3];
  }
  float c = (float)cnt;
  a0 /= c; a1 /= c; a2 /= c; a3 /= c;
  if (OUTF32) {
    float4 o = {a0, a1, a2, a3};
    ((float4*)(outf + (size_t)node * 256))[lane] = o;
  } else {
    bf16x4 o = {(bf16)a0, (bf16)a1, (bf16)a2, (bf16)a3};
    ((bf16x4*)(outb + (size_t)node * 256))[lane] = o;
  }
}

// ---------------- Q = ea @ WieT + bias (K=64 streaming GEMM) ----------------
// 512 threads, BM=128, BN=256; 8 waves 2x4, per-wave 64x64, acc[4][4].
__global__ __launch_bounds__(512) void gemm_ea(
    const float* __restrict__ ea, const bf16* __restrict__ Wt /*[256][64]*/,
    const float* __restrict__ bias, bf16* __restrict__ out, int Mrows) {
  __shared__ __align__(16) bf16 As[128 * 64];   // 16 KB
  __shared__ __align__(16) bf16 Bs[256 * 64];   // 32 KB
  const int tid = threadIdx.x;
  const int lane = tid & 63;
  const int wave = tid >> 6;
  const int wm = wave >> 2, wn = wave & 3;
  const int m0 = blockIdx.x * 128;

  // stage A: 128 rows x 8 chunks(16B) = 1024 units, 2 per thread
#pragma unroll
  for (int r = 0; r < 2; ++r) {
    int unit = r * 512 + tid;
    int row = unit >> 3, u = unit & 7;
    int rr = m0 + row;
    if (rr >= Mrows) rr = Mrows - 1;
    const float* g = ea + (size_t)rr * 64 + u * 8;
    float4 a = *(const float4*)g, b = *(const float4*)(g + 4);
    bf16x8 v = {(bf16)a.x, (bf16)a.y, (bf16)a.z, (bf16)a.w,
                (bf16)b.x, (bf16)b.y, (bf16)b.z, (bf16)b.w};
    int pos = u ^ (row & 7);
    *(bf16x8*)(&As[((size_t)row * 8 + pos) * 8]) = v;
  }
  // stage B: 256 cols x 8 chunks = 2048 units, 4 per thread
#pragma unroll
  for (int r = 0; r < 4; ++r) {
    int unit = r * 512 + tid;
    int col = unit >> 3, u = unit & 7;
    int us = u ^ (col & 7);
    gload16(Wt + (size_t)col * 64 + us * 8, &Bs[(size_t)(r * 512 + wave * 64) * 8]);
  }
  f32x4 acc[4][4];
#pragma unroll
  for (int i = 0; i < 4; ++i)
#pragma unroll
    for (int j = 0; j < 4; ++j) acc[i][j] = (f32x4){0.f, 0.f, 0.f, 0.f};
  __syncthreads();
#pragma unroll
  for (int s = 0; s < 2; ++s) {
    int kq = s * 4 + (lane >> 4);
    bf16x8 af[4], bfr[4];
#pragma unroll
    for (int i = 0; i < 4; ++i) {
      int ar = wm * 64 + i * 16 + (lane & 15);
      af[i] = *(const bf16x8*)(&As[((size_t)ar * 8 + (kq ^ (ar & 7))) * 8]);
    }
#pragma unroll
    for (int j = 0; j < 4; ++j) {
      int bc = wn * 64 + j * 16 + (lane & 15);
      bfr[j] = *(const bf16x8*)(&Bs[((size_t)bc * 8 + (kq ^ (bc & 7))) * 8]);
    }
#pragma unroll
    for (int i = 0; i < 4; ++i)
#pragma unroll
      for (int j = 0; j < 4; ++j)
        acc[i][j] = __builtin_amdgcn_mfma_f32_16x16x32_bf16(af[i], bfr[j], acc[i][j], 0, 0, 0);
  }
#pragma unroll
  for (int i = 0; i < 4; ++i) {
    int rbase = m0 + wm * 64 + i * 16 + ((lane >> 4) << 2);
#pragma unroll
    for (int j = 0; j < 4; ++j) {
      int col = wn * 64 + j * 16 + (lane & 15);
      float bcol = bias[col];
#pragma unroll
      for (int r = 0; r < 4; ++r) {
        int row = rbase + r;
        if (row < Mrows) out[(size_t)row * 256 + col] = (bf16)(acc[i][j][r] + bcol);
      }
    }
  }
}

// ---------------- full-B gather GEMM: K=256, BM=128, 2 col-passes --------------
// 512 threads, 8 waves 2x4. As[128][256] 64KB + Bs[128][256] 64KB = 128KB LDS.
// A rows gathered once as 512B bursts; Bs restaged between col-passes.
// SRC 0: A row rr (identity, from Af f32 or Ab bf16)
// SRC 1: A row = x[src[rr]]
// SRC 2: A row = agg[src[rr]] - Hb[rev[rr]] (both bf16)
// epilogue: + (ADDROW ? addrow[row] : 0) + (bias?bias[col]:0), RELU optional
template <int SRC, int XF32, int ADDROW, int RELU>
__global__ __launch_bounds__(512) void gemm_fullB(
    const float* __restrict__ Af, const bf16* __restrict__ Ab, const bf16* __restrict__ Hb,
    const bf16* __restrict__ Wt /*[256][256]*/, const float* __restrict__ bias,
    const bf16* __restrict__ addrow, const int* __restrict__ srcIdx,
    const int* __restrict__ revIdx, bf16* out, int Mrows, int Nsrc) {
  __shared__ __align__(16) bf16 As[128 * 256];
  __shared__ __align__(16) bf16 Bs[128 * 256];
  const int tid = threadIdx.x;
  const int lane = tid & 63;
  const int wave = tid >> 6;
  const int wm = wave >> 2, wn = wave & 3;
  const int m0 = blockIdx.x * 128;

  // ---- stage A: 2 row-passes x 64 rows, 8 threads/row, 4x16B bursts/thread ----
  const int rid = tid >> 3, lane8 = tid & 7;
#pragma unroll
  for (int rp = 0; rp < 2; ++rp) {
    int row = rp * 64 + rid;
    int rr = m0 + row;
    if (rr >= Mrows) rr = Mrows - 1;
    int swz = lane8 ^ (row & 7);
    if (SRC == 2) {
      const bf16* ga = Ab + (size_t)clampi(srcIdx[rr], Nsrc) * 256;
      const bf16* gh = Hb + (size_t)clampi(revIdx[rr], Mrows) * 256;
      float4 pa[4], ph[4];
#pragma unroll
      for (int st = 0; st < 4; ++st) {
        pa[st] = *(const float4*)(ga + (lane8 + 8 * st) * 8);
        ph[st] = *(const float4*)(gh + (lane8 + 8 * st) * 8);
      }
#pragma unroll
      for (int st = 0; st < 4; ++st) {
        bf16x8 va = *(bf16x8*)&pa[st];
        bf16x8 vh = *(bf16x8*)&ph[st];
        bf16x8 v;
#pragma unroll
        for (int j = 0; j < 8; ++j) v[j] = (bf16)((float)va[j] - (float)vh[j]);
        *(bf16x8*)(&As[((size_t)row * 32 + st * 8 + swz) * 8]) = v;
      }
    } else {
      int rsrc = (SRC == 1) ? clampi(srcIdx[rr], Nsrc) : rr;
      if (XF32) {
        const float* g = Af + (size_t)rsrc * 256;
        float4 p[4][2];
#pragma unroll
        for (int st = 0; st < 4; ++st) {
          const float* gg = g + (lane8 + 8 * st) * 8;
          p[st][0] = *(const float4*)gg;
          p[st][1] = *(const float4*)(gg + 4);
        }
#pragma unroll
        for (int st = 0; st < 4; ++st) {
          const float* f = (const float*)&p[st][0];
          bf16x8 v;
#pragma unroll
          for (int j = 0; j < 8; ++j) v[j] = (bf16)f[j];
          *(bf16x8*)(&As[((size_t)row * 32 + st * 8 + swz) * 8]) = v;
        }
      } else {
        const bf16* g = Ab + (size_t)rsrc * 256;
        float4 p[4];
#pragma unroll
        for (int st = 0; st < 4; ++st) p[st] = *(const float4*)(g + (lane8 + 8 * st) * 8);
#pragma unroll
        for (int st = 0; st < 4; ++st)
          *(bf16x8*)(&As[((size_t)row * 32 + st * 8 + swz) * 8]) = *(bf16x8*)&p[st];
      }
    }
  }

  f32x4 acc[4][2];
#pragma unroll
  for (int p = 0; p < 2; ++p) {
    // ---- stage B for col-pass p: 128 cols x 32 chunks = 4096 units, 8/thread ----
#pragma unroll
    for (int r = 0; r < 8; ++r) {
      int unit = r * 512 + tid;
      int col = unit >> 5, cu = unit & 31;
      int cus = (cu & 24) | ((cu & 7) ^ (col & 7));
      gload16(Wt + (size_t)(p * 128 + col) * 256 + cus * 8,
              &Bs[(size_t)(r * 512 + wave * 64) * 8]);
    }
#pragma unroll
    for (int i = 0; i < 4; ++i)
#pragma unroll
      for (int j = 0; j < 2; ++j) acc[i][j] = (f32x4){0.f, 0.f, 0.f, 0.f};
    __syncthreads();  // A ds_writes (p=0) + B loads visible
    // ---- compute ----
#pragma unroll
    for (int kc = 0; kc < 4; ++kc) {
#pragma unroll
      for (int s = 0; s < 2; ++s) {
        int kq = s * 4 + (lane >> 4);
        bf16x8 af[4], bfr[2];
#pragma unroll
        for (int i = 0; i < 4; ++i) {
          int ar = wm * 64 + i * 16 + (lane & 15);
          af[i] = *(const bf16x8*)(&As[((size_t)ar * 32 + kc * 8 + (kq ^ (ar & 7))) * 8]);
        }
#pragma unroll
        for (int j = 0; j < 2; ++j) {
          int bc = wn * 32 + j * 16 + (lane & 15);
          bfr[j] = *(const bf16x8*)(&Bs[((size_t)bc * 32 + kc * 8 + (kq ^ (bc & 7))) * 8]);
        }
#pragma unroll
        for (int i = 0; i < 4; ++i)
#pragma unroll
          for (int j = 0; j < 2; ++j)
            acc[i][j] = __builtin_amdgcn_mfma_f32_16x16x32_bf16(af[i], bfr[j], acc[i][j], 0, 0, 0);
      }
    }
    // ---- epilogue for pass p ----
#pragma unroll
    for (int i = 0; i < 4; ++i) {
      int rbase = m0 + wm * 64 + i * 16 + ((lane >> 4) << 2);
#pragma unroll
      for (int j = 0; j < 2; ++j) {
        int col = p * 128 + wn * 32 + j * 16 + (lane & 15);
        float bcol = bias ? bias[col] : 0.f;
#pragma unroll
        for (int r = 0; r < 4; ++r) {
          int row = rbase + r;
          if (row < Mrows) {
            float v = acc[i][j][r] + bcol;
            if (ADDROW) v += (float)addrow[(size_t)row * 256 + col];
            if (RELU) v = fmaxf(v, 0.f);
            out[(size_t)row * 256 + col] = (bf16)v;
          }
        }
      }
    }
    if (p == 0) __syncthreads();  // all waves done reading Bs before restage
  }
}

// ---------------- per-level driver ----------------
template <int XF32>
static void run_level(const float* xf, const bf16* xb, const float* ea,
                      const int* src, const int* dst, const int* rev, int E, int N, int depth,
                      const bf16* WixT, const bf16* WieT, const float* bi_,
                      const bf16* WhT, const float* bh_,
                      const bf16* WoxT, const bf16* WomT, const float* bo_,
                      bf16* C, bf16* Dd, bf16* Ee, bf16* agg, bf16* h,
                      int* cnt, int* incl, int* offs, int* cursr, int* bsums, int* bexcl,
                      int* elist, hipStream_t stream) {
  // CSR build
  hipMemsetAsync(cnt, 0, (size_t)N * 4, stream);
  hist_kernel<<<(E + 255) / 256, 256, 0, stream>>>(dst, E, cnt, N);
  int nb = (N + 1023) / 1024;
  scan_block_kernel<<<nb, 256, 0, stream>>>(cnt, N, incl, bsums);
  scan_sums_kernel<<<1, 256, 0, stream>>>(bsums, nb, bexcl);
  scan_add_kernel<<<(N + 255) / 256, 256, 0, stream>>>(incl, bexcl, N, offs);
  hipMemsetAsync(cursr, 0, (size_t)N * 4, stream);
  scatter_kernel<<<(E + 255) / 256, 256, 0, stream>>>(dst, E, offs, cursr, elist, N);

  dim3 ge((E + 127) / 128);
  // Q = ea @ WieT + bi -> Dd (dead buffer pre-iteration)
  gemm_ea<<<ge, 512, 0, stream>>>(ea, WieT, bi_, Dd, E);
  // H0 = relu(x[src] @ WixT + Q) -> C
  gemm_fullB<1, XF32, 1, 1><<<ge, 512, 0, stream>>>(xf, xb, nullptr, WixT, nullptr, Dd, src,
                                                    nullptr, C, E, N);
  bf16* Hcur = C;
  for (int it = 0; it < depth - 1; ++it) {
    segsum_kernel<0, 0><<<(N + 3) / 4, 256, 0, stream>>>(Hcur, elist, offs, nullptr, nullptr,
                                                         agg, N);
    bf16* Hn = (it == depth - 2) ? C : ((it & 1) ? Ee : Dd);  // last iter in-place over H0
    // H_next = relu(H0 + (agg[src] - Hcur[rev]) @ WhT + bh)
    gemm_fullB<2, 0, 1, 1><<<ge, 512, 0, stream>>>(nullptr, agg, Hcur, WhT, bh_, C, src, rev,
                                                   Hn, E, N);
    Hcur = Hn;
  }
  segsum_kernel<1, XF32><<<(N + 3) / 4, 256, 0, stream>>>(Hcur, elist, offs, xf, xb, agg, N);
  dim3 gn((N + 127) / 128);
  // t = x @ WoxT + bo -> Dd (dead again); h = relu(M @ WomT + t)
  gemm_fullB<0, XF32, 0, 0><<<gn, 512, 0, stream>>>(xf, xb, nullptr, WoxT, bo_, nullptr,
                                                    nullptr, nullptr, Dd, N, N);
  gemm_fullB<0, 0, 1, 1><<<gn, 512, 0, stream>>>(nullptr, agg, nullptr, WomT, nullptr, Dd,
                                                 nullptr, nullptr, h, N, N);
}

// ---------------- host ----------------
extern "C" void kernel_launch(void* const* d_in, const int* in_sizes, int n_in,
                              void* d_out, int out_size, void* d_ws, size_t ws_size,
                              hipStream_t stream) {
  constexpr int N1 = 102400, E1 = 300000;
  constexpr int N2 = 10240, E2 = 40960;
  constexpr int N3 = 1024, E3 = 4096;
  constexpr int G = 64;

  const float* x   = (const float*)d_in[0];
  const float* ea1 = (const float*)d_in[1];
  const float* ea2 = (const float*)d_in[2];
  const float* ea3 = (const float*)d_in[3];
  const int* ei1 = (const int*)d_in[4];
  const int* rv1 = (const int*)d_in[5];
  const int* ei2 = (const int*)d_in[6];
  const int* rv2 = (const int*)d_in[7];
  const int* ei3 = (const int*)d_in[8];
  const int* rv3 = (const int*)d_in[9];
  const float *Wi[3], *bi[3], *Wh[3], *bh[3], *Wo[3], *bo[3];
  for (int l = 0; l < 3; ++l) {
    Wi[l] = (const float*)d_in[13 + 6 * l + 0];
    bi[l] = (const float*)d_in[13 + 6 * l + 1];
    Wh[l] = (const float*)d_in[13 + 6 * l + 2];
    bh[l] = (const float*)d_in[13 + 6 * l + 3];
    Wo[l] = (const float*)d_in[13 + 6 * l + 4];
    bo[l] = (const float*)d_in[13 + 6 * l + 5];
  }
  float* outp = (float*)d_out;
  char* ws = (char*)d_ws;

  size_t off = 0;
  auto alloc = [&](size_t b) { size_t o = off; off += (b + 255) & ~(size_t)255; return o; };
  size_t o_wix[3], o_wie[3], o_wh[3], o_wox[3], o_wom[3];
  for (int l = 0; l < 3; ++l) {
    o_wix[l] = alloc((size_t)256 * 256 * 2);
    o_wie[l] = alloc((size_t)256 * 64 * 2);
    o_wh[l]  = alloc((size_t)256 * 256 * 2);
    o_wox[l] = alloc((size_t)256 * 256 * 2);
    o_wom[l] = alloc((size_t)256 * 256 * 2);
  }
  size_t o_C   = alloc((size_t)E1 * 256 * 2);  // H0 / in-place H_final / h1
  size_t o_D   = alloc((size_t)E1 * 256 * 2);  // Q / ping / t
  size_t o_E3b = alloc((size_t)E3 * 256 * 2);  // level-3 (depth 4) pong buffer
  size_t o_agg = alloc((size_t)N1 * 256 * 2);
  size_t o_x2  = alloc((size_t)N2 * 256 * 2);
  size_t o_h2  = alloc((size_t)N2 * 256 * 2);
  size_t o_x3  = alloc((size_t)N3 * 256 * 2);
  size_t o_h3  = alloc((size_t)N3 * 256 * 2);
  size_t o_cnt = alloc((size_t)N1 * 4);
  size_t o_inc = alloc((size_t)N1 * 4);
  size_t o_off = alloc((size_t)(N1 + 1) * 4);
  size_t o_cur = alloc((size_t)N1 * 4);
  size_t o_bs  = alloc(1024 * 4);
  size_t o_bx  = alloc(1024 * 4);
  size_t o_el  = alloc((size_t)E1 * 4);

  if (ws_size < off) {  // workspace too small: fail cleanly, don't fault
    hipMemsetAsync(d_out, 0, (size_t)out_size * 4, stream);
    return;
  }

  int* cnt   = (int*)(ws + o_cnt);
  int* incl  = (int*)(ws + o_inc);
  int* offs  = (int*)(ws + o_off);
  int* cursr = (int*)(ws + o_cur);
  int* bsums = (int*)(ws + o_bs);
  int* bexcl = (int*)(ws + o_bx);
  int* elist = (int*)(ws + o_el);
  bf16* C    = (bf16*)(ws + o_C);
  bf16* Dd   = (bf16*)(ws + o_D);
  bf16* E3b  = (bf16*)(ws + o_E3b);
  bf16* agg  = (bf16*)(ws + o_agg);
  bf16* x2b  = (bf16*)(ws + o_x2);
  bf16* h2b  = (bf16*)(ws + o_h2);
  bf16* x3b  = (bf16*)(ws + o_x3);
  bf16* h3b  = (bf16*)(ws + o_h3);

  for (int l = 0; l < 3; ++l) {
    wtcvtT_kernel<<<(256 * 256 + 255) / 256, 256, 0, stream>>>(Wi[l], (bf16*)(ws + o_wix[l]),
                                                               256, 0);
    wtcvtT_kernel<<<(64 * 256 + 255) / 256, 256, 0, stream>>>(Wi[l], (bf16*)(ws + o_wie[l]),
                                                              64, 256);
    wtcvtT_kernel<<<(256 * 256 + 255) / 256, 256, 0, stream>>>(Wh[l], (bf16*)(ws + o_wh[l]),
                                                               256, 0);
    wtcvtT_kernel<<<(256 * 256 + 255) / 256, 256, 0, stream>>>(Wo[l], (bf16*)(ws + o_wox[l]),
                                                               256, 0);
    wtcvtT_kernel<<<(256 * 256 + 255) / 256, 256, 0, stream>>>(Wo[l], (bf16*)(ws + o_wom[l]),
                                                               256, 256);
  }

  // level 1 (x f32)
  run_level<1>(x, nullptr, ea1, ei1, ei1 + E1, rv1, E1, N1, 3,
               (bf16*)(ws + o_wix[0]), (bf16*)(ws + o_wie[0]), bi[0],
               (bf16*)(ws + o_wh[0]), bh[0],
               (bf16*)(ws + o_wox[0]), (bf16*)(ws + o_wom[0]), bo[0],
               C, Dd, Dd, agg, C,
               cnt, incl, offs, cursr, bsums, bexcl, elist, stream);
  pool_kernel<0><<<(N2 + 3) / 4, 256, 0, stream>>>(C, x2b, nullptr, N2, N1 / N2);

  // level 2
  run_level<0>(nullptr, x2b, ea2, ei2, ei2 + E2, rv2, E2, N2, 3,
               (bf16*)(ws + o_wix[1]), (bf16*)(ws + o_wie[1]), bi[1],
               (bf16*)(ws + o_wh[1]), bh[1],
               (bf16*)(ws + o_wox[1]), (bf16*)(ws + o_wom[1]), bo[1],
               C, Dd, Dd, agg, h2b,
               cnt, incl, offs, cursr, bsums, bexcl, elist, stream);
  pool_kernel<0><<<(N3 + 3) / 4, 256, 0, stream>>>(h2b, x3b, nullptr, N3, N2 / N3);

  // level 3 (depth 4 -> needs distinct pong buffer E3b)
  run_level<0>(nullptr, x3b, ea3, ei3, ei3 + E3, rv3, E3, N3, 4,
               (bf16*)(ws + o_wix[2]), (bf16*)(ws + o_wie[2]), bi[2],
               (bf16*)(ws + o_wh[2]), bh[2],
               (bf16*)(ws + o_wox[2]), (bf16*)(ws + o_wom[2]), bo[2],
               C, Dd, E3b, agg, h3b,
               cnt, incl, offs, cursr, bsums, bexcl, elist, stream);
  pool_kernel<1><<<(G + 3) / 4, 256, 0, stream>>>(h3b, nullptr, outp, G, N3 / G);
}

// Round 11
// 1646.264 us; speedup vs baseline: 1.1534x; 1.1534x over previous
//
#include <hip/hip_runtime.h>
#include <stdint.h>

typedef __bf16 bf16;
typedef __bf16 bf16x4 __attribute__((ext_vector_type(4)));
typedef __bf16 bf16x8 __attribute__((ext_vector_type(8)));
typedef float  f32x4  __attribute__((ext_vector_type(4)));

__device__ __forceinline__ int clampi(int v, int n) { return (v < 0 || v >= n) ? 0 : v; }

__device__ __forceinline__ void gload16(const void* g, void* l) {
  __builtin_amdgcn_global_load_lds((const __attribute__((address_space(1))) void*)g,
                                   (__attribute__((address_space(3))) void*)l, 16, 0, 0);
}

// W [rows][256] f32 -> Wt [256][krows] bf16 (transpose of row-slice [krow0, krow0+krows))
__global__ void wtcvtT_kernel(const float* __restrict__ W, bf16* __restrict__ Wt,
                              int krows, int krow0) {
  int idx = blockIdx.x * 256 + threadIdx.x;
  if (idx >= krows * 256) return;
  int k = idx >> 8, n = idx & 255;
  Wt[(size_t)n * krows + k] = (bf16)W[(size_t)(krow0 + k) * 256 + n];
}

// ---------------- CSR build ----------------
__global__ void hist_kernel(const int* __restrict__ dst, int E, int* __restrict__ cnt, int N) {
  int e = blockIdx.x * 256 + threadIdx.x;
  if (e < E) atomicAdd(&cnt[clampi(dst[e], N)], 1);
}

__global__ void scan_block_kernel(const int* __restrict__ cnt, int N,
                                  int* __restrict__ incl, int* __restrict__ bsums) {
  __shared__ int sd[256];
  int t = threadIdx.x, bid = blockIdx.x;
  int base = bid * 1024 + t * 4;
  int v0 = (base + 0 < N) ? cnt[base + 0] : 0;
  int v1 = (base + 1 < N) ? cnt[base + 1] : 0;
  int v2 = (base + 2 < N) ? cnt[base + 2] : 0;
  int v3 = (base + 3 < N) ? cnt[base + 3] : 0;
  int s1 = v0 + v1, s2 = s1 + v2, s3 = s2 + v3;
  sd[t] = s3;
  __syncthreads();
  for (int off = 1; off < 256; off <<= 1) {
    int x = 0;
    if (t >= off) x = sd[t - off];
    __syncthreads();
    sd[t] += x;
    __syncthreads();
  }
  int excl = sd[t] - s3;
  if (base + 0 < N) incl[base + 0] = excl + v0;
  if (base + 1 < N) incl[base + 1] = excl + s1;
  if (base + 2 < N) incl[base + 2] = excl + s2;
  if (base + 3 < N) incl[base + 3] = excl + s3;
  if (t == 255) bsums[bid] = sd[255];
}

__global__ void scan_sums_kernel(const int* __restrict__ bsums, int nb, int* __restrict__ bexcl) {
  __shared__ int sd[256];
  int t = threadIdx.x;
  int v = (t < nb) ? bsums[t] : 0;
  sd[t] = v;
  __syncthreads();
  for (int off = 1; off < 256; off <<= 1) {
    int x = 0;
    if (t >= off) x = sd[t - off];
    __syncthreads();
    sd[t] += x;
    __syncthreads();
  }
  if (t < nb) bexcl[t] = sd[t] - v;
}

__global__ void scan_add_kernel(const int* __restrict__ incl, const int* __restrict__ bexcl,
                                int N, int* __restrict__ offs) {
  int i = blockIdx.x * 256 + threadIdx.x;
  if (i < N) offs[i + 1] = incl[i] + bexcl[i >> 10];
  if (i == 0) offs[0] = 0;
}

__global__ void scatter_kernel(const int* __restrict__ dst, int E, const int* __restrict__ offs,
                               int* __restrict__ cursor, int* __restrict__ elist, int N) {
  int e = blockIdx.x * 256 + threadIdx.x;
  if (e < E) {
    int d = clampi(dst[e], N);
    int p = atomicAdd(&cursor[d], 1);
    elist[offs[d] + p] = e;
  }
}

// ---------------- segment sum (one wave per node, 4 cols/lane) ----------------
template <int WHERE, int XF32>
__global__ void segsum_kernel(const bf16* __restrict__ H, const int* __restrict__ elist,
                              const int* __restrict__ offs, const float* __restrict__ xf,
                              const bf16* __restrict__ xb, bf16* __restrict__ out, int N) {
  int lane = threadIdx.x & 63;
  int node = blockIdx.x * 4 + (threadIdx.x >> 6);
  if (node >= N) return;
  int beg = offs[node], end = offs[node + 1];
  float a0 = 0.f, a1 = 0.f, a2 = 0.f, a3 = 0.f;
  for (int p = beg; p < end; ++p) {
    int e = elist[p];
    bf16x4 v = ((const bf16x4*)(H + (size_t)e * 256))[lane];
    a0 += (float)v[0]; a1 += (float)v[1]; a2 += (float)v[2]; a3 += (float)v[3];
  }
  if (WHERE) {
    float s = a0 + a1 + a2 + a3;
    for (int off = 1; off < 64; off <<= 1) s += __shfl_xor(s, off);
    if (s == 0.f) {  // no (nonzero) incoming messages -> pass through x
      bf16x4 o;
      if (XF32) {
        float4 xv = ((const float4*)(xf))[(size_t)node * 64 + lane];
        o[0] = (bf16)xv.x; o[1] = (bf16)xv.y; o[2] = (bf16)xv.z; o[3] = (bf16)xv.w;
      } else {
        o = ((const bf16x4*)(xb + (size_t)node * 256))[lane];
      }
      ((bf16x4*)(out + (size_t)node * 256))[lane] = o;
      return;
    }
  }
  bf16x4 o = {(bf16)a0, (bf16)a1, (bf16)a2, (bf16)a3};
  ((bf16x4*)(out + (size_t)node * 256))[lane] = o;
}

// ---------------- mean pool over contiguous groups ----------------
template <int OUTF32>
__global__ void pool_kernel(const bf16* __restrict__ h, bf16* __restrict__ outb,
                            float* __restrict__ outf, int Nout, int cnt) {
  int lane = threadIdx.x & 63;
  int node = blockIdx.x * 4 + (threadIdx.x >> 6);
  if (node >= Nout) return;
  float a0 = 0.f, a1 = 0.f, a2 = 0.f, a3 = 0.f;
  size_t base = (size_t)node * cnt;
  for (int p = 0; p < cnt; ++p) {
    bf16x4 v = ((const bf16x4*)(h + (base + p) * 256))[lane];
    a0 += (float)v[0]; a1 += (float)v[1]; a2 += (float)v[2]; a3 += (float)v[3];
  }
  float c = (float)cnt;
  a0 /= c; a1 /= c; a2 /= c; a3 /= c;
  if (OUTF32) {
    float4 o = {a0, a1, a2, a3};
    ((float4*)(outf + (size_t)node * 256))[lane] = o;
  } else {
    bf16x4 o = {(bf16)a0, (bf16)a1, (bf16)a2, (bf16)a3};
    ((bf16x4*)(outb + (size_t)node * 256))[lane] = o;
  }
}

// ---------------- streaming GEMM, K=256, BM=128, BN=256 ----------------
// 512 thr (8 waves 2x4), per-wave 64x64, acc[4][4]. LDS dbuf 96 KB, 1 barrier/tile.
// A: sequential rows (or via aIdx — coalesced when idx is shift-structured).
// AF32: A read as f32 (reg-staged cvt); else bf16 via global_load_lds.
// EPI 0: out = acc (+bias)
// EPI 1: out = relu(addrow[row] + grow[gIdx[row]] - acc + bias)   [combine; out may alias addrow]
// EPI 2: out = relu(acc + addrow[row])
template <int AF32, int AIDX, int EPI>
__global__ __launch_bounds__(512) void sgemm(
    const float* __restrict__ Af, const bf16* __restrict__ Ab, const int* __restrict__ aIdx,
    const bf16* __restrict__ Wt /*[256][256]*/, const float* __restrict__ bias,
    const bf16* __restrict__ addrow, const bf16* __restrict__ grow,
    const int* __restrict__ gIdx, bf16* out, int Mrows, int NsrcA, int NsrcG) {
  constexpr int NK = 4;
  __shared__ __align__(16) bf16 As[2][128 * 64];
  __shared__ __align__(16) bf16 Bs[2][256 * 64];
  const int tid = threadIdx.x, lane = tid & 63, wave = tid >> 6;
  const int wm = wave >> 2, wn = wave & 3;
  const int m0 = blockIdx.x * 128;

  int rowA[2], uA[2], abase[2];
#pragma unroll
  for (int r = 0; r < 2; ++r) {
    int unit = r * 512 + tid;
    rowA[r] = unit >> 3;
    uA[r] = unit & 7;
    int rr = m0 + rowA[r];
    if (rr >= Mrows) rr = Mrows - 1;
    int ar = AIDX ? clampi(aIdx[rr], NsrcA) : rr;
    abase[r] = ar * 256;
  }

  f32x4 acc[4][4];
#pragma unroll
  for (int i = 0; i < 4; ++i)
#pragma unroll
    for (int j = 0; j < 4; ++j) acc[i][j] = (f32x4){0.f, 0.f, 0.f, 0.f};
  float4 pf[2][2];

  auto issueB = [&](int kc, int buf) {
#pragma unroll
    for (int r = 0; r < 4; ++r) {
      int unit = r * 512 + tid;
      int row = unit >> 3, us = (unit & 7) ^ (row & 7);
      gload16(Wt + (size_t)row * 256 + kc * 64 + us * 8, &Bs[buf][(r * 512 + wave * 64) * 8]);
    }
  };
  auto issueA = [&](int kc, int buf) {
#pragma unroll
    for (int r = 0; r < 2; ++r) {
      int us = uA[r] ^ (rowA[r] & 7);
      gload16(Ab + (size_t)(abase[r] + kc * 64 + us * 8), &As[buf][(r * 512 + wave * 64) * 8]);
    }
  };
  auto loadAreg = [&](int kc) {
#pragma unroll
    for (int r = 0; r < 2; ++r) {
      const float* g = Af + (size_t)(abase[r] + kc * 64 + uA[r] * 8);
      pf[r][0] = *(const float4*)g;
      pf[r][1] = *(const float4*)(g + 4);
    }
  };
  auto writeAreg = [&](int buf) {
#pragma unroll
    for (int r = 0; r < 2; ++r) {
      int us = uA[r] ^ (rowA[r] & 7);
      const float* f = (const float*)&pf[r][0];
      bf16x8 v;
#pragma unroll
      for (int j = 0; j < 8; ++j) v[j] = (bf16)f[j];
      *(bf16x8*)(&As[buf][((size_t)rowA[r] * 8 + us) * 8]) = v;
    }
  };

  issueB(0, 0);
  if (AF32) { loadAreg(0); writeAreg(0); } else issueA(0, 0);
  int cur = 0;
  for (int kc = 0; kc < NK; ++kc) {
    __syncthreads();  // tile kc staged (vmcnt+lgkm drained at barrier)
    if (kc + 1 < NK) {
      issueB(kc + 1, cur ^ 1);
      if (AF32) loadAreg(kc + 1); else issueA(kc + 1, cur ^ 1);
    }
    const bf16* Asb = As[cur];
    const bf16* Bsb = Bs[cur];
#pragma unroll
    for (int s = 0; s < 2; ++s) {
      int kq = s * 4 + (lane >> 4);
      bf16x8 af[4], bfr[4];
#pragma unroll
      for (int i = 0; i < 4; ++i) {
        int ar = wm * 64 + i * 16 + (lane & 15);
        af[i] = *(const bf16x8*)(&Asb[(size_t)ar * 64 + (size_t)(kq ^ (ar & 7)) * 8]);
      }
#pragma unroll
      for (int j = 0; j < 4; ++j) {
        int br = wn * 64 + j * 16 + (lane & 15);
        bfr[j] = *(const bf16x8*)(&Bsb[(size_t)br * 64 + (size_t)(kq ^ (br & 7)) * 8]);
      }
#pragma unroll
      for (int i = 0; i < 4; ++i)
#pragma unroll
        for (int j = 0; j < 4; ++j)
          acc[i][j] = __builtin_amdgcn_mfma_f32_16x16x32_bf16(af[i], bfr[j], acc[i][j], 0, 0, 0);
    }
    if (AF32 && kc + 1 < NK) writeAreg(cur ^ 1);
    cur ^= 1;
  }
  // ---- epilogue ----
#pragma unroll
  for (int i = 0; i < 4; ++i) {
    int rbase = m0 + wm * 64 + i * 16 + ((lane >> 4) << 2);
#pragma unroll
    for (int r = 0; r < 4; ++r) {
      int row = rbase + r;
      if (row >= Mrows) continue;
      int gs = (EPI == 1) ? clampi(gIdx[row], NsrcG) : 0;
#pragma unroll
      for (int j = 0; j < 4; ++j) {
        int col = wn * 64 + j * 16 + (lane & 15);
        float v = acc[i][j][r];
        if (EPI == 0) {
          if (bias) v += bias[col];
        } else if (EPI == 1) {
          v = (float)addrow[(size_t)row * 256 + col] + (float)grow[(size_t)gs * 256 + col] - v +
              bias[col];
          v = fmaxf(v, 0.f);
        } else {
          v = fmaxf(v + (float)addrow[(size_t)row * 256 + col], 0.f);
        }
        out[(size_t)row * 256 + col] = (bf16)v;
      }
    }
  }
}

// ---------------- H0 GEMM: K=64 (ea f32) + epilogue gather of xW[src] ------------
// out = relu(ea @ WieT + bias + xW[src[row]]), 512 thr, BM=128, BN=256.
__global__ __launch_bounds__(512) void gemm_ea64(
    const float* __restrict__ ea, const bf16* __restrict__ Wt /*[256][64]*/,
    const float* __restrict__ bias, const bf16* __restrict__ grow,
    const int* __restrict__ gIdx, bf16* __restrict__ out, int Mrows, int NsrcG) {
  __shared__ __align__(16) bf16 As[128 * 64];
  __shared__ __align__(16) bf16 Bs[256 * 64];
  const int tid = threadIdx.x, lane = tid & 63, wave = tid >> 6;
  const int wm = wave >> 2, wn = wave & 3;
  const int m0 = blockIdx.x * 128;

#pragma unroll
  for (int r = 0; r < 2; ++r) {
    int unit = r * 512 + tid;
    int row = unit >> 3, u = unit & 7;
    int rr = m0 + row;
    if (rr >= Mrows) rr = Mrows - 1;
    const float* g = ea + (size_t)rr * 64 + u * 8;
    float4 a = *(const float4*)g, b = *(const float4*)(g + 4);
    bf16x8 v = {(bf16)a.x, (bf16)a.y, (bf16)a.z, (bf16)a.w,
                (bf16)b.x, (bf16)b.y, (bf16)b.z, (bf16)b.w};
    int pos = u ^ (row & 7);
    *(bf16x8*)(&As[((size_t)row * 8 + pos) * 8]) = v;
  }
#pragma unroll
  for (int r = 0; r < 4; ++r) {
    int unit = r * 512 + tid;
    int col = unit >> 3, u = unit & 7;
    int us = u ^ (col & 7);
    gload16(Wt + (size_t)col * 64 + us * 8, &Bs[(size_t)(r * 512 + wave * 64) * 8]);
  }
  f32x4 acc[4][4];
#pragma unroll
  for (int i = 0; i < 4; ++i)
#pragma unroll
    for (int j = 0; j < 4; ++j) acc[i][j] = (f32x4){0.f, 0.f, 0.f, 0.f};
  __syncthreads();
#pragma unroll
  for (int s = 0; s < 2; ++s) {
    int kq = s * 4 + (lane >> 4);
    bf16x8 af[4], bfr[4];
#pragma unroll
    for (int i = 0; i < 4; ++i) {
      int ar = wm * 64 + i * 16 + (lane & 15);
      af[i] = *(const bf16x8*)(&As[((size_t)ar * 8 + (kq ^ (ar & 7))) * 8]);
    }
#pragma unroll
    for (int j = 0; j < 4; ++j) {
      int bc = wn * 64 + j * 16 + (lane & 15);
      bfr[j] = *(const bf16x8*)(&Bs[((size_t)bc * 8 + (kq ^ (bc & 7))) * 8]);
    }
#pragma unroll
    for (int i = 0; i < 4; ++i)
#pragma unroll
      for (int j = 0; j < 4; ++j)
        acc[i][j] = __builtin_amdgcn_mfma_f32_16x16x32_bf16(af[i], bfr[j], acc[i][j], 0, 0, 0);
  }
#pragma unroll
  for (int i = 0; i < 4; ++i) {
    int rbase = m0 + wm * 64 + i * 16 + ((lane >> 4) << 2);
#pragma unroll
    for (int r = 0; r < 4; ++r) {
      int row = rbase + r;
      if (row >= Mrows) continue;
      int gs = clampi(gIdx[row], NsrcG);
#pragma unroll
      for (int j = 0; j < 4; ++j) {
        int col = wn * 64 + j * 16 + (lane & 15);
        float v = acc[i][j][r] + bias[col] + (float)grow[(size_t)gs * 256 + col];
        out[(size_t)row * 256 + col] = (bf16)fmaxf(v, 0.f);
      }
    }
  }
}

// ---------------- per-level driver ----------------
// All GEMMs streaming. Per iter: agg=segsum(H); aggW=agg@Wh (in-place);
// Hnext = relu(H0 + aggW[src] - (H[rev])@Wh + bh)  [combine sgemm].
template <int XF32>
static void run_level(const float* xf, const bf16* xb, const float* ea,
                      const int* src, const int* dst, const int* rev, int E, int N, int depth,
                      const bf16* WixT, const bf16* WieT, const float* bi_,
                      const bf16* WhT, const float* bh_,
                      const bf16* WoxT, const bf16* WomT, const float* bo_,
                      bf16* C, bf16* Dd, bf16* Ee, bf16* nbuf, bf16* tb, bf16* hb,
                      int* cnt, int* incl, int* offs, int* cursr, int* bsums, int* bexcl,
                      int* elist, hipStream_t stream) {
  // CSR build
  hipMemsetAsync(cnt, 0, (size_t)N * 4, stream);
  hist_kernel<<<(E + 255) / 256, 256, 0, stream>>>(dst, E, cnt, N);
  int nb = (N + 1023) / 1024;
  scan_block_kernel<<<nb, 256, 0, stream>>>(cnt, N, incl, bsums);
  scan_sums_kernel<<<1, 256, 0, stream>>>(bsums, nb, bexcl);
  scan_add_kernel<<<(N + 255) / 256, 256, 0, stream>>>(incl, bexcl, N, offs);
  hipMemsetAsync(cursr, 0, (size_t)N * 4, stream);
  scatter_kernel<<<(E + 255) / 256, 256, 0, stream>>>(dst, E, offs, cursr, elist, N);

  dim3 ge((E + 127) / 128), gn((N + 127) / 128);
  // xW = x @ WixT -> nbuf
  sgemm<XF32, 0, 0><<<gn, 512, 0, stream>>>(xf, xb, nullptr, WixT, nullptr, nullptr, nullptr,
                                            nullptr, nbuf, N, N, 0);
  // H0 = relu(ea @ WieT + bi + xW[src]) -> C
  gemm_ea64<<<ge, 512, 0, stream>>>(ea, WieT, bi_, nbuf, src, C, E, N);

  bf16* Hcur = C;
  for (int it = 0; it < depth - 1; ++it) {
    // agg = segsum(Hcur) -> nbuf ; aggW = agg @ WhT (in-place)
    segsum_kernel<0, 0><<<(N + 3) / 4, 256, 0, stream>>>(Hcur, elist, offs, nullptr, nullptr,
                                                         nbuf, N);
    sgemm<0, 0, 0><<<gn, 512, 0, stream>>>(nullptr, nbuf, nullptr, WhT, nullptr, nullptr,
                                           nullptr, nullptr, nbuf, N, N, 0);
    bf16* Hn = (it == depth - 2) ? C : ((it & 1) ? Ee : Dd);  // last iter in-place over H0
    // Hn = relu(H0 + aggW[src] - (Hcur[rev])@WhT + bh)
    sgemm<0, 1, 1><<<ge, 512, 0, stream>>>(nullptr, Hcur, rev, WhT, bh_, C, nbuf, src, Hn, E,
                                           E, N);
    Hcur = Hn;
  }
  // M -> nbuf (with where-fallback to x)
  segsum_kernel<1, XF32><<<(N + 3) / 4, 256, 0, stream>>>(Hcur, elist, offs, xf, xb, nbuf, N);
  // t = x @ WoxT + bo -> tb ; h = relu(M @ WomT + t) -> hb
  sgemm<XF32, 0, 0><<<gn, 512, 0, stream>>>(xf, xb, nullptr, WoxT, bo_, nullptr, nullptr,
                                            nullptr, tb, N, N, 0);
  sgemm<0, 0, 2><<<gn, 512, 0, stream>>>(nullptr, nbuf, nullptr, WomT, nullptr, tb, nullptr,
                                         nullptr, hb, N, N, 0);
}

// ---------------- host ----------------
extern "C" void kernel_launch(void* const* d_in, const int* in_sizes, int n_in,
                              void* d_out, int out_size, void* d_ws, size_t ws_size,
                              hipStream_t stream) {
  constexpr int N1 = 102400, E1 = 300000;
  constexpr int N2 = 10240, E2 = 40960;
  constexpr int N3 = 1024, E3 = 4096;
  constexpr int G = 64;

  const float* x   = (const float*)d_in[0];
  const float* ea1 = (const float*)d_in[1];
  const float* ea2 = (const float*)d_in[2];
  const float* ea3 = (const float*)d_in[3];
  const int* ei1 = (const int*)d_in[4];
  const int* rv1 = (const int*)d_in[5];
  const int* ei2 = (const int*)d_in[6];
  const int* rv2 = (const int*)d_in[7];
  const int* ei3 = (const int*)d_in[8];
  const int* rv3 = (const int*)d_in[9];
  const float *Wi[3], *bi[3], *Wh[3], *bh[3], *Wo[3], *bo[3];
  for (int l = 0; l < 3; ++l) {
    Wi[l] = (const float*)d_in[13 + 6 * l + 0];
    bi[l] = (const float*)d_in[13 + 6 * l + 1];
    Wh[l] = (const float*)d_in[13 + 6 * l + 2];
    bh[l] = (const float*)d_in[13 + 6 * l + 3];
    Wo[l] = (const float*)d_in[13 + 6 * l + 4];
    bo[l] = (const float*)d_in[13 + 6 * l + 5];
  }
  float* outp = (float*)d_out;
  char* ws = (char*)d_ws;

  size_t off = 0;
  auto alloc = [&](size_t b) { size_t o = off; off += (b + 255) & ~(size_t)255; return o; };
  size_t o_wix[3], o_wie[3], o_wh[3], o_wox[3], o_wom[3];
  for (int l = 0; l < 3; ++l) {
    o_wix[l] = alloc((size_t)256 * 256 * 2);
    o_wie[l] = alloc((size_t)256 * 64 * 2);
    o_wh[l]  = alloc((size_t)256 * 256 * 2);
    o_wox[l] = alloc((size_t)256 * 256 * 2);
    o_wom[l] = alloc((size_t)256 * 256 * 2);
  }
  size_t o_C  = alloc((size_t)E1 * 256 * 2);  // H0 / in-place H_final; t at base after death
  size_t o_D  = alloc((size_t)E1 * 256 * 2);  // H iterate; h at base after death
  size_t o_nb = alloc((size_t)N1 * 256 * 2);  // xW / agg / aggW / M
  size_t o_cnt = alloc((size_t)N1 * 4);
  size_t o_inc = alloc((size_t)N1 * 4);
  size_t o_off = alloc((size_t)(N1 + 1) * 4);
  size_t o_cur = alloc((size_t)N1 * 4);
  size_t o_bs  = alloc(1024 * 4);
  size_t o_bx  = alloc(1024 * 4);
  size_t o_el  = alloc((size_t)E1 * 4);

  if (ws_size < off) {  // workspace too small: fail cleanly, don't fault
    hipMemsetAsync(d_out, 0, (size_t)out_size * 4, stream);
    return;
  }

  int* cnt   = (int*)(ws + o_cnt);
  int* incl  = (int*)(ws + o_inc);
  int* offs  = (int*)(ws + o_off);
  int* cursr = (int*)(ws + o_cur);
  int* bsums = (int*)(ws + o_bs);
  int* bexcl = (int*)(ws + o_bx);
  int* elist = (int*)(ws + o_el);
  bf16* C    = (bf16*)(ws + o_C);
  bf16* Dd   = (bf16*)(ws + o_D);
  bf16* nbuf = (bf16*)(ws + o_nb);
  // small buffers aliased into C/D tails (level-2/3 touch only the first E2*256=10.5M
  // elems of C/D; offsets below are >= 32M elems, safely beyond)
  const size_t M32 = (size_t)32 * 1024 * 1024;
  bf16* x2b = C + M32;              // level-2 input, survives level 2
  bf16* x3b = C + M32 + 4 * 1024 * 1024;   // level-3 input
  bf16* E3b = Dd + M32;             // level-3 depth-4 pong (E3-sized)
  bf16* h3b = Dd + M32 + 4 * 1024 * 1024;  // level-3 h output

  for (int l = 0; l < 3; ++l) {
    wtcvtT_kernel<<<(256 * 256 + 255) / 256, 256, 0, stream>>>(Wi[l], (bf16*)(ws + o_wix[l]),
                                                               256, 0);
    wtcvtT_kernel<<<(64 * 256 + 255) / 256, 256, 0, stream>>>(Wi[l], (bf16*)(ws + o_wie[l]),
                                                              64, 256);
    wtcvtT_kernel<<<(256 * 256 + 255) / 256, 256, 0, stream>>>(Wh[l], (bf16*)(ws + o_wh[l]),
                                                               256, 0);
    wtcvtT_kernel<<<(256 * 256 + 255) / 256, 256, 0, stream>>>(Wo[l], (bf16*)(ws + o_wox[l]),
                                                               256, 0);
    wtcvtT_kernel<<<(256 * 256 + 255) / 256, 256, 0, stream>>>(Wo[l], (bf16*)(ws + o_wom[l]),
                                                               256, 256);
  }

  // ---- level 1 (x f32). t -> C base (after H_final consumed), h -> D base.
  run_level<1>(x, nullptr, ea1, ei1, ei1 + E1, rv1, E1, N1, 3,
               (bf16*)(ws + o_wix[0]), (bf16*)(ws + o_wie[0]), bi[0],
               (bf16*)(ws + o_wh[0]), bh[0],
               (bf16*)(ws + o_wox[0]), (bf16*)(ws + o_wom[0]), bo[0],
               C, Dd, Dd, nbuf, C, Dd,
               cnt, incl, offs, cursr, bsums, bexcl, elist, stream);
  pool_kernel<0><<<(N2 + 3) / 4, 256, 0, stream>>>(Dd, x2b, nullptr, N2, N1 / N2);

  // ---- level 2
  run_level<0>(nullptr, x2b, ea2, ei2, ei2 + E2, rv2, E2, N2, 3,
               (bf16*)(ws + o_wix[1]), (bf16*)(ws + o_wie[1]), bi[1],
               (bf16*)(ws + o_wh[1]), bh[1],
               (bf16*)(ws + o_wox[1]), (bf16*)(ws + o_wom[1]), bo[1],
               C, Dd, Dd, nbuf, C, Dd,
               cnt, incl, offs, cursr, bsums, bexcl, elist, stream);
  pool_kernel<0><<<(N3 + 3) / 4, 256, 0, stream>>>(Dd, x3b, nullptr, N3, N2 / N3);

  // ---- level 3 (depth 4; pong E3b; h -> h3b to keep x3b intact)
  run_level<0>(nullptr, x3b, ea3, ei3, ei3 + E3, rv3, E3, N3, 4,
               (bf16*)(ws + o_wix[2]), (bf16*)(ws + o_wie[2]), bi[2],
               (bf16*)(ws + o_wh[2]), bh[2],
               (bf16*)(ws + o_wox[2]), (bf16*)(ws + o_wom[2]), bo[2],
               C, Dd, E3b, nbuf, C, h3b,
               cnt, incl, offs, cursr, bsums, bexcl, elist, stream);
  pool_kernel<1><<<(G + 3) / 4, 256, 0, stream>>>(h3b, nullptr, outp, G, N3 / G);
}